// Round 12
// baseline (328.419 us; speedup 1.0000x reference)
//
#include <hip/hip_runtime.h>
#include <hip/hip_bf16.h>

typedef short s16x8 __attribute__((ext_vector_type(8)));
typedef float f32x16 __attribute__((ext_vector_type(16)));

namespace {
constexpr int kB = 16;
constexpr int kD = 256;
constexpr int kHW = 16384;
constexpr int kM = 4096;
constexpr int kN = kB * kM;              // 65536 samples
constexpr int kKT = 32;                  // K-tile columns
constexpr float kLam = 0.005f;

__device__ __forceinline__ unsigned short f2bf(float f) {
    union { float f; unsigned u; } x{f};
    const unsigned r = x.u + 0x7FFFu + ((x.u >> 16) & 1u);
    return (unsigned short)(r >> 16);
}
}

// barrier without vmcnt drain (prefetches stay in flight)
#define BAR_SOFT()                                            \
    do {                                                      \
        asm volatile("s_waitcnt lgkmcnt(0)" ::: "memory");    \
        __builtin_amdgcn_s_barrier();                         \
    } while (0)

// ---------------------------------------------------------------------------
// Kernel 1: per-b histogram of flat_idx -> counts c[b][p].
// ---------------------------------------------------------------------------
__global__ __launch_bounds__(256) void count_kernel(
    const int* __restrict__ flat_idx, int* __restrict__ cnt)
{
    __shared__ int h[kHW];
    const int t = threadIdx.x;
    const int b = blockIdx.x;
    for (int i = t; i < kHW; i += 256) h[i] = 0;
    __syncthreads();
    const int* bi = flat_idx + b * kM;
    for (int i = t; i < kM; i += 256) atomicAdd(&h[bi[i]], 1);
    __syncthreads();
    int* dst = cnt + b * kHW;
    for (int i = t; i < kHW; i += 256) dst[i] = h[i];
}

// ---------------------------------------------------------------------------
// Kernel 2: fused stream + weighted Gram + stats.
// 1024 threads (16 waves), 256x256 Gram tile, acc=64 AGPR/wave ->
// 2 blocks/CU (32 waves).  Staging: 8 lanes x 16B = 128B contiguous per row
// per wave-op (2x the 64B granularity of R6-R11).  kKT=32 double-buffered
// LDS (2x32KB) + early loads + BAR_SOFT (no vmcnt drain), 1 barrier/iter.
// ---------------------------------------------------------------------------
__global__ __launch_bounds__(1024, 2) void fused_gram_kernel(
    const float* __restrict__ z, const float* __restrict__ zp,
    const int* __restrict__ cnt,
    float* __restrict__ partial, float* __restrict__ statsPart,
    int winCols)
{
    __shared__ char smem[65536];   // buf0: A 16K | B 16K ; buf1 @ 32K

    const int bx = blockIdx.x;
    const int b = bx & (kB - 1);
    const int win0 = (bx >> 4) * winCols;
    const int nIter = winCols / kKT;
    const int t = threadIdx.x;
    const int w = t >> 6, lane = t & 63, l31 = lane & 31, half = lane >> 5;
    const int wr = w >> 2;          // 0..3 row block of 64
    const int wc = w & 3;           // 0..3 col block of 64
    const int srow = t >> 3;        // 0..127 staging row
    const int scol = (t & 7) * 4;   // f32 col within 32-col tile
    const int sslotA = (scol >> 3); // 0..3 k-group of this thread's float4

    const float* zb  = z  + (size_t)b * kD * kHW;
    const float* zpb = zp + (size_t)b * kD * kHW;
    const int* cb = cnt + b * kHW;

    f32x16 acc[2][2];
#pragma unroll
    for (int i = 0; i < 2; ++i)
#pragma unroll
        for (int j = 0; j < 2; ++j)
#pragma unroll
            for (int r = 0; r < 16; ++r) acc[i][j][r] = 0.f;

    float sA[2], ssA[2], sB[2], ssB[2];
    sA[0] = sA[1] = ssA[0] = ssA[1] = 0.f;
    sB[0] = sB[1] = ssB[0] = ssB[1] = 0.f;

    float4 va[2], vb[2];
    int4 ci;

    auto LOAD = [&](int kt) {
        const int base = win0 + kt * kKT + scol;
#pragma unroll
        for (int q = 0; q < 2; ++q) {
            const int row = srow + 128 * q;
            va[q] = *(const float4*)(zb  + (size_t)row * kHW + base);
            vb[q] = *(const float4*)(zpb + (size_t)row * kHW + base);
        }
        ci = *(const int4*)(cb + base);
    };

    // LDS: element (row, c) at (row*4 + ((c>>3) ^ ((row>>1)&3)))*16 + (c&7)*2
    auto CONV = [&](int buf) {
        char* As = smem + buf * 32768;
        char* Bs = As + 16384;
        const float cf[4] = {(float)ci.x, (float)ci.y, (float)ci.z, (float)ci.w};
#pragma unroll
        for (int q = 0; q < 2; ++q) {
            const int row = srow + 128 * q;
            const int slot = sslotA ^ ((row >> 1) & 3);
            const int off = ((row * 4 + slot) << 4) + ((scol & 7) << 1);
            const float a[4] = {va[q].x, va[q].y, va[q].z, va[q].w};
            const float bbv[4] = {vb[q].x, vb[q].y, vb[q].z, vb[q].w};
            ushort4 pa, pb;
            unsigned short* pav = (unsigned short*)&pa;
            unsigned short* pbv = (unsigned short*)&pb;
#pragma unroll
            for (int j = 0; j < 4; ++j) {
                const float wb = cf[j] * bbv[j];
                sA[q]  = fmaf(cf[j], a[j], sA[q]);
                ssA[q] = fmaf(cf[j], a[j] * a[j], ssA[q]);
                sB[q]  = fmaf(cf[j], bbv[j], sB[q]);
                ssB[q] = fmaf(cf[j], bbv[j] * bbv[j], ssB[q]);
                pav[j] = f2bf(a[j]);     // A raw
                pbv[j] = f2bf(wb);       // B weighted
            }
            *(unsigned long long*)(As + off) = *(unsigned long long*)&pa;
            *(unsigned long long*)(Bs + off) = *(unsigned long long*)&pb;
        }
    };

    auto MFMA_STEP = [&](int buf) {
        const char* As = smem + buf * 32768;
        const char* Bs = As + 16384;
#pragma unroll
        for (int ks = 0; ks < 2; ++ks) {
            const int kg = 2 * ks + half;
            s16x8 af[2], bfr[2];
#pragma unroll
            for (int rt = 0; rt < 2; ++rt) {
                const int row = 64 * wr + 32 * rt + l31;
                const int slot = kg ^ ((row >> 1) & 3);
                af[rt] = *(const s16x8*)(As + ((row * 4 + slot) << 4));
            }
#pragma unroll
            for (int ct = 0; ct < 2; ++ct) {
                const int row = 64 * wc + 32 * ct + l31;
                const int slot = kg ^ ((row >> 1) & 3);
                bfr[ct] = *(const s16x8*)(Bs + ((row * 4 + slot) << 4));
            }
#pragma unroll
            for (int rt = 0; rt < 2; ++rt)
#pragma unroll
                for (int ct = 0; ct < 2; ++ct)
                    acc[rt][ct] = __builtin_amdgcn_mfma_f32_32x32x16_bf16(
                        af[rt], bfr[ct], acc[rt][ct], 0, 0, 0);
        }
    };

    // Prologue
    LOAD(0);
    CONV(0);
    LOAD(1);
    BAR_SOFT();

    for (int kt = 0; kt < nIter; ++kt) {
        if (kt + 1 < nIter) CONV((kt + 1) & 1);   // consumes regs -> frees them
        if (kt + 2 < nIter) LOAD(kt + 2);         // issue early, ~1.5 iter slack
        MFMA_STEP(kt & 1);
        BAR_SOFT();
    }
    __syncthreads();   // full drain before smem reuse

    // 256x256 partial Gram
    float* out = partial + (size_t)bx * (kD * kD);
#pragma unroll
    for (int rt = 0; rt < 2; ++rt)
#pragma unroll
        for (int ct = 0; ct < 2; ++ct)
#pragma unroll
            for (int r = 0; r < 16; ++r) {
                const int row = 64 * wr + 32 * rt + (r & 3) + 8 * (r >> 2) + 4 * half;
                const int col = 64 * wc + 32 * ct + l31;
                out[row * kD + col] = acc[rt][ct][r];
            }

    // stats reduce via (dead) LDS: sd[256 rows][8 groups][4 kinds] = 32KB
    float* sd = (float*)smem;
#pragma unroll
    for (int q = 0; q < 2; ++q) {
        const int row = srow + 128 * q;
        float* p = sd + (row * 8 + (t & 7)) * 4;
        p[0] = sA[q]; p[1] = ssA[q]; p[2] = sB[q]; p[3] = ssB[q];
    }
    __syncthreads();
    {
        const int row = t >> 2;        // 0..255
        const int kind = t & 3;
        float v = 0.f;
#pragma unroll
        for (int g = 0; g < 8; ++g) v += sd[(row * 8 + g) * 4 + kind];
        statsPart[((size_t)bx * kD + row) * 4 + kind] = v;
    }
}

// ---------------------------------------------------------------------------
// Kernel 3: reduce partial Grams -> G; statsPart -> statsRed.
// ---------------------------------------------------------------------------
__global__ __launch_bounds__(256) void reduce_gram_kernel(
    const float* __restrict__ partial, const float* __restrict__ statsPart,
    float* __restrict__ G, float* __restrict__ statsRed, int nPart)
{
    const int d = blockIdx.x;
    const int e = threadIdx.x;
    float s = 0.f;
    for (int c = 0; c < nPart; ++c)
        s += partial[(size_t)c * (kD * kD) + d * kD + e];
    G[d * kD + e] = s;

    // stats: thread e accumulates slabs e, e+256, ... then cross-lane reduce
    float x0 = 0.f, x1 = 0.f, x2 = 0.f, x3 = 0.f;
    for (int c = e; c < nPart; c += 256) {
        const float4 v = *(const float4*)(statsPart + ((size_t)c * kD + d) * 4);
        x0 += v.x; x1 += v.y; x2 += v.z; x3 += v.w;
    }
#pragma unroll
    for (int o = 32; o; o >>= 1) {
        x0 += __shfl_down(x0, o);
        x1 += __shfl_down(x1, o);
        x2 += __shfl_down(x2, o);
        x3 += __shfl_down(x3, o);
    }
    __shared__ float r[4][4];
    if ((e & 63) == 0) {
        r[e >> 6][0] = x0; r[e >> 6][1] = x1;
        r[e >> 6][2] = x2; r[e >> 6][3] = x3;
    }
    __syncthreads();
    if (e < 4) {
        statsRed[d * 4 + e] = r[0][e] + r[1][e] + r[2][e] + r[3][e];
    }
}

// ---------------------------------------------------------------------------
// Kernel 4: final loss (single block).
// ---------------------------------------------------------------------------
__global__ __launch_bounds__(256) void loss_kernel(
    const float* __restrict__ G, const float* __restrict__ statsRed,
    float* __restrict__ out)
{
    __shared__ float muA[kD], isA[kD], muB[kD], isB[kD];
    const int t = threadIdx.x;
    const float4 v = *(const float4*)(statsRed + t * 4);
    const float n = (float)kN;
    const float mA = v.x / n, mB = v.z / n;
    const float vA = (v.y - n * mA * mA) / (n - 1.f);
    const float vB = (v.w - n * mB * mB) / (n - 1.f);
    const float sdA = fmaxf(sqrtf(fmaxf(vA, 0.f)), 1e-6f);
    const float sdB = fmaxf(sqrtf(fmaxf(vB, 0.f)), 1e-6f);
    muA[t] = mA; isA[t] = 1.f / sdA;
    muB[t] = mB; isB[t] = 1.f / sdB;
    __syncthreads();

    float acc = 0.f;
    for (int d = 0; d < kD; ++d) {
        const int e = t;
        const float c = (G[d * kD + e] / n - muA[d] * muB[e]) * isA[d] * isB[e];
        if (d == e) { const float u = 1.f - c; acc += u * u; }
        else        { acc += kLam * c * c; }
    }
#pragma unroll
    for (int o = 32; o; o >>= 1) acc += __shfl_down(acc, o);
    __shared__ float r[4];
    if ((t & 63) == 0) r[t >> 6] = acc;
    __syncthreads();
    if (t == 0) out[0] = r[0] + r[1] + r[2] + r[3];
}

// ---------------------------------------------------------------------------
extern "C" void kernel_launch(void* const* d_in, const int* in_sizes, int n_in,
                              void* d_out, int out_size, void* d_ws, size_t ws_size,
                              hipStream_t stream) {
    const float* z  = (const float*)d_in[0];
    const float* zp = (const float*)d_in[1];
    const int* flat_idx = (const int*)d_in[2];
    float* out = (float*)d_out;

    char* ws = (char*)d_ws;
    // ws layout:
    //   [0, 1MB)        counts  int [16][16384]
    //   [1MB, 3MB)      statsPart f32 [nPart<=512][256][4]
    //   [3MB, +4K)      statsRed f32 [256][4]
    //   [3MB+64K,+256K) G f32 [256][256]
    //   [16MB, ...)     partial f32 [nPart][256][256]  (128MB at nPart=512)
    int* cnt = (int*)ws;
    float* statsPart = (float*)(ws + (size_t)1 * 1024 * 1024);
    float* statsRed  = (float*)(ws + (size_t)3 * 1024 * 1024);
    float* G = (float*)(ws + (size_t)3 * 1024 * 1024 + 64 * 1024);
    float* partial = (float*)(ws + (size_t)16 * 1024 * 1024);

    // 512 blocks (2/CU) needs 16MB + 512*256KB = 144MB of ws; else fall back.
    const bool big = ws_size >= (size_t)146 * 1024 * 1024;
    const int nWin = big ? 32 : 16;
    const int winCols = kHW / nWin;          // 512 or 1024
    const int nBlk = kB * nWin;              // 512 or 256

    count_kernel<<<kB, 256, 0, stream>>>(flat_idx, cnt);
    fused_gram_kernel<<<nBlk, 1024, 0, stream>>>(z, zp, cnt, partial, statsPart, winCols);
    reduce_gram_kernel<<<kD, 256, 0, stream>>>(partial, statsPart, G, statsRed, nBlk);
    loss_kernel<<<1, 256, 0, stream>>>(G, statsRed, out);
}